// Round 2
// baseline (96.911 us; speedup 1.0000x reference)
//
#include <hip/hip_runtime.h>

typedef __attribute__((ext_vector_type(8))) _Float16 f16x8;
typedef __attribute__((ext_vector_type(4))) _Float16 f16x4;
typedef __attribute__((ext_vector_type(4))) float f32x4;

#define NB 16
#define MAXC 256
#define MAXT 4096
#define HID 512
#define NSRC 256
#define TT 64

// gelu(x) ~= x * sigmoid(1.5957691x + 0.0713548x^3)   (tanh-form, |err| ~3e-4)
__device__ __forceinline__ float gelu_fast(float x) {
  float p = x * x;
  float q = __builtin_fmaf(p, -0.10294336f, -2.30220778f);
  float e = __builtin_amdgcn_exp2f(x * q);
  return x * __builtin_amdgcn_rcpf(1.0f + e);
}

// (R x C) fp32 -> (C x R) fp16, one 32x32 tile per block, blockIdx.z = matrix idx
__global__ void transpose_cvt_kernel(const float* __restrict__ src,
                                     _Float16* __restrict__ dst, int R, int C) {
  __shared__ float tile[32][33];
  const float* s = src + (size_t)blockIdx.z * R * C;
  _Float16* d = dst + (size_t)blockIdx.z * R * C;
  int c0 = blockIdx.x * 32, r0 = blockIdx.y * 32;
  int tx = threadIdx.x, ty = threadIdx.y;
  for (int i = ty; i < 32; i += 8)
    tile[i][tx] = s[(size_t)(r0 + i) * C + (c0 + tx)];
  __syncthreads();
  for (int i = ty; i < 32; i += 8)
    d[(size_t)(c0 + i) * R + (r0 + tx)] = (_Float16)tile[tx][i];
}

// One workgroup = one (batch, 64-wide time tile). 8 waves, 1 WG/CU.
// Phase A: GEMM1-ch0  |  Phase B: GEMM2-ch0 + GEMM1-ch1 (merged)  |  Phase C: GEMM2-ch1
// All weight A-fragments register-prefetched one phase ahead (explicit, since
// __syncthreads drains vmcnt and the compiler never hoists across barriers).
__global__ __launch_bounds__(512, 2)
void fused_sess_proj_kernel(const float* __restrict__ x,
                            const int* __restrict__ sess_ids,
                            const int* __restrict__ seq_lens,
                            const _Float16* __restrict__ W1t,   // [8][HID][MAXC]
                            const float* __restrict__ b_sess,   // [8][HID]
                            const _Float16* __restrict__ W2t,   // [NSRC][HID]
                            const float* __restrict__ b2,       // [NSRC]
                            float* __restrict__ out) {
  int wg = blockIdx.x;
  int b = wg >> 6;
  int t0 = (wg & 63) * TT;
  int seqlen = seq_lens[b];
  int tid = threadIdx.x;

  if (t0 >= seqlen) {  // fully masked tile: just write zeros (d_out is poisoned)
    int row = tid >> 1;
    int part = tid & 1;
    float* po = out + ((size_t)b * NSRC + row) * MAXT + t0 + part * 32;
    f32x4 z = {0.f, 0.f, 0.f, 0.f};
    #pragma unroll
    for (int i = 0; i < 8; ++i) *(f32x4*)(po + i * 4) = z;
    return;
  }

  // swizzled [t][col] layouts: elem idx = t*256 + (col ^ ((t&7)<<3))
  __shared__ _Float16 Xs[TT * MAXC];     // 32 KB
  __shared__ _Float16 Hs[2][TT * 256];   // 64 KB double-buffered h chunks

  int lane = tid & 63;
  int w = tid >> 6;    // wave 0..7
  int lg = lane >> 4;  // k-group / row-group
  int lr = lane & 15;  // m-row (A) / n-col (B,D)
  int sid = sess_ids[b];
  const _Float16* W1s = W1t + (size_t)sid * HID * MAXC;

  // ---- weight fragment prefetch buffers (register arrays, static indexing) ----
  f16x8 AF1[8][2];  // GEMM1 A-frags for current chunk
  f16x8 AF2[8][2];  // GEMM2 A-frags for current chunk
  #pragma unroll
  for (int ks = 0; ks < 8; ++ks)
    #pragma unroll
    for (int mi = 0; mi < 2; ++mi) {
      AF1[ks][mi] = *(const f16x8*)(W1s +
          (size_t)(w * 32 + mi * 16 + lr) * MAXC + ks * 32 + lg * 8);
      AF2[ks][mi] = *(const f16x8*)(W2t +
          (size_t)(w * 32 + mi * 16 + lr) * HID + ks * 32 + lg * 8);
    }

  // ---- stage X^T tile as fp16 (lane-per-channel; coalesced global reads) ----
  {
    int c = tid & 255;
    int th = tid >> 8;  // 0..1 halves of the 64 times
    const float* xp = x + ((size_t)b * MAXC + c) * MAXT + t0 + th * 32;
    #pragma unroll
    for (int i = 0; i < 8; ++i) {
      f32x4 v = *(const f32x4*)(xp + i * 4);
      #pragma unroll
      for (int k = 0; k < 4; ++k) {
        int t = th * 32 + i * 4 + k;
        Xs[t * 256 + (c ^ ((t & 7) << 3))] = (_Float16)v[k];
      }
    }
  }

  // accumulators: acc2 persists across both chunks (bias-init)
  f32x4 acc2[2][4], acc1[2][4];
  #pragma unroll
  for (int mi = 0; mi < 2; ++mi) {
    f32x4 bv2 = *(const f32x4*)(b2 + w * 32 + mi * 16 + lg * 4);
    f32x4 bv1 = *(const f32x4*)(b_sess + sid * HID + w * 32 + mi * 16 + lg * 4);
    #pragma unroll
    for (int ni = 0; ni < 4; ++ni) { acc2[mi][ni] = bv2; acc1[mi][ni] = bv1; }
  }

  __syncthreads();  // bar1: Xs ready (also drains weight prefetch, already issued)

  // ================= Phase A: GEMM1-ch0 (Xs, AF1=ch0) =================
  #pragma unroll
  for (int ks = 0; ks < 8; ++ks) {
    int k0 = ks * 32;
    f16x8 bf[4];
    #pragma unroll
    for (int ni = 0; ni < 4; ++ni) {
      int t = ni * 16 + lr;
      bf[ni] = *(const f16x8*)(&Xs[t * 256 + ((k0 + lg * 8) ^ ((t & 7) << 3))]);
    }
    #pragma unroll
    for (int mi = 0; mi < 2; ++mi)
      #pragma unroll
      for (int ni = 0; ni < 4; ++ni)
        acc1[mi][ni] = __builtin_amdgcn_mfma_f32_16x16x32_f16(AF1[ks][mi], bf[ni], acc1[mi][ni], 0, 0, 0);
    // refill AF1 with ch1 fragments (used in Phase B, after bar2)
    #pragma unroll
    for (int mi = 0; mi < 2; ++mi)
      AF1[ks][mi] = *(const f16x8*)(W1s +
          (size_t)(256 + w * 32 + mi * 16 + lr) * MAXC + k0 + lg * 8);
  }

  // ---- gelu(acc1) -> Hs[0]; re-init acc1 with ch1 bias ----
  #pragma unroll
  for (int mi = 0; mi < 2; ++mi) {
    int hh = w * 32 + mi * 16 + lg * 4;
    #pragma unroll
    for (int ni = 0; ni < 4; ++ni) {
      int t = ni * 16 + lr;
      f16x4 g;
      #pragma unroll
      for (int r = 0; r < 4; ++r) g[r] = (_Float16)gelu_fast(acc1[mi][ni][r]);
      *(f16x4*)(&Hs[0][t * 256 + (hh ^ ((t & 7) << 3))]) = g;
    }
  }
  #pragma unroll
  for (int mi = 0; mi < 2; ++mi) {
    f32x4 bv1 = *(const f32x4*)(b_sess + sid * HID + 256 + w * 32 + mi * 16 + lg * 4);
    #pragma unroll
    for (int ni = 0; ni < 4; ++ni) acc1[mi][ni] = bv1;
  }

  __syncthreads();  // bar2: Hs[0] ready

  // ============ Phase B: GEMM2-ch0 (Hs[0], AF2=ch0) + GEMM1-ch1 (Xs, AF1=ch1) ============
  #pragma unroll
  for (int ks = 0; ks < 8; ++ks) {
    int k0 = ks * 32;
    {
      f16x8 bf[4];
      #pragma unroll
      for (int ni = 0; ni < 4; ++ni) {
        int t = ni * 16 + lr;
        bf[ni] = *(const f16x8*)(&Hs[0][t * 256 + ((k0 + lg * 8) ^ ((t & 7) << 3))]);
      }
      #pragma unroll
      for (int mi = 0; mi < 2; ++mi)
        #pragma unroll
        for (int ni = 0; ni < 4; ++ni)
          acc2[mi][ni] = __builtin_amdgcn_mfma_f32_16x16x32_f16(AF2[ks][mi], bf[ni], acc2[mi][ni], 0, 0, 0);
    }
    // refill AF2 with ch1 fragments (used in Phase C, after bar3)
    #pragma unroll
    for (int mi = 0; mi < 2; ++mi)
      AF2[ks][mi] = *(const f16x8*)(W2t +
          (size_t)(w * 32 + mi * 16 + lr) * HID + 256 + k0 + lg * 8);
    {
      f16x8 bf[4];
      #pragma unroll
      for (int ni = 0; ni < 4; ++ni) {
        int t = ni * 16 + lr;
        bf[ni] = *(const f16x8*)(&Xs[t * 256 + ((k0 + lg * 8) ^ ((t & 7) << 3))]);
      }
      #pragma unroll
      for (int mi = 0; mi < 2; ++mi)
        #pragma unroll
        for (int ni = 0; ni < 4; ++ni)
          acc1[mi][ni] = __builtin_amdgcn_mfma_f32_16x16x32_f16(AF1[ks][mi], bf[ni], acc1[mi][ni], 0, 0, 0);
    }
  }

  // ---- gelu(acc1) -> Hs[1] (other buffer; Phase-B readers done with Hs[0] per-wave) ----
  #pragma unroll
  for (int mi = 0; mi < 2; ++mi) {
    int hh = w * 32 + mi * 16 + lg * 4;
    #pragma unroll
    for (int ni = 0; ni < 4; ++ni) {
      int t = ni * 16 + lr;
      f16x4 g;
      #pragma unroll
      for (int r = 0; r < 4; ++r) g[r] = (_Float16)gelu_fast(acc1[mi][ni][r]);
      *(f16x4*)(&Hs[1][t * 256 + (hh ^ ((t & 7) << 3))]) = g;
    }
  }

  __syncthreads();  // bar3: Hs[1] ready

  // ================= Phase C: GEMM2-ch1 (Hs[1], AF2=ch1) =================
  #pragma unroll
  for (int ks = 0; ks < 8; ++ks) {
    int k0 = ks * 32;
    f16x8 bf[4];
    #pragma unroll
    for (int ni = 0; ni < 4; ++ni) {
      int t = ni * 16 + lr;
      bf[ni] = *(const f16x8*)(&Hs[1][t * 256 + ((k0 + lg * 8) ^ ((t & 7) << 3))]);
    }
    #pragma unroll
    for (int mi = 0; mi < 2; ++mi)
      #pragma unroll
      for (int ni = 0; ni < 4; ++ni)
        acc2[mi][ni] = __builtin_amdgcn_mfma_f32_16x16x32_f16(AF2[ks][mi], bf[ni], acc2[mi][ni], 0, 0, 0);
  }

  // ---- epilogue: time mask + fp32 store ----
  #pragma unroll
  for (int mi = 0; mi < 2; ++mi) {
    int s0 = w * 32 + mi * 16 + lg * 4;
    #pragma unroll
    for (int ni = 0; ni < 4; ++ni) {
      int t = t0 + ni * 16 + lr;
      float m = (t < seqlen) ? 1.0f : 0.0f;
      #pragma unroll
      for (int r = 0; r < 4; ++r)
        out[((size_t)b * NSRC + s0 + r) * MAXT + t] = acc2[mi][ni][r] * m;
    }
  }
}

extern "C" void kernel_launch(void* const* d_in, const int* in_sizes, int n_in,
                              void* d_out, int out_size, void* d_ws, size_t ws_size,
                              hipStream_t stream) {
  const float* x      = (const float*)d_in[0];
  const int* sess     = (const int*)d_in[1];
  // d_in[2] = channel_counts: unused (x is already zero-padded past true channels)
  const int* seq      = (const int*)d_in[3];
  const float* W_sess = (const float*)d_in[4];
  const float* b_sess = (const float*)d_in[5];
  const float* W2     = (const float*)d_in[6];
  const float* b2     = (const float*)d_in[7];
  float* out = (float*)d_out;

  _Float16* W1t = (_Float16*)d_ws;                               // [8][512][256]
  _Float16* W2t = (_Float16*)((char*)d_ws + (size_t)8 * HID * MAXC * sizeof(_Float16));

  dim3 tb(32, 8);
  // W_sess: per session (256 x 512) -> (512 x 256) fp16
  transpose_cvt_kernel<<<dim3(HID / 32, MAXC / 32, 8), tb, 0, stream>>>(W_sess, W1t, MAXC, HID);
  // W2: (512 x 256) -> (256 x 512) fp16
  transpose_cvt_kernel<<<dim3(NSRC / 32, HID / 32, 1), tb, 0, stream>>>(W2, W2t, HID, NSRC);

  fused_sess_proj_kernel<<<dim3(NB * (MAXT / TT)), dim3(512), 0, stream>>>(
      x, sess, seq, W1t, b_sess, W2t, b2, out);
}

// Round 4
// 94.375 us; speedup vs baseline: 1.0269x; 1.0269x over previous
//
#include <hip/hip_runtime.h>

typedef __attribute__((ext_vector_type(8))) _Float16 f16x8;
typedef __attribute__((ext_vector_type(4))) _Float16 f16x4;
typedef __attribute__((ext_vector_type(2))) __fp16 fp16v2;  // cvt_pkrtz result type
typedef __attribute__((ext_vector_type(4))) float f32x4;

#define NB 16
#define MAXC 256
#define MAXT 4096
#define HID 512
#define NSRC 256
#define TT 64

// Barrier WITHOUT vmcnt drain: LDS writes (lgkm) must be visible, but
// register-destined global loads may stay in flight across the barrier.
#define BAR() asm volatile("s_waitcnt lgkmcnt(0)\n\ts_barrier" ::: "memory")

// gelu(x) ~= x * sigmoid(1.5957691x + 0.0713548x^3)   (tanh-form, |err| ~3e-4)
__device__ __forceinline__ float gelu_fast(float x) {
  float p = x * x;
  float q = __builtin_fmaf(p, -0.10294336f, -2.30220778f);
  float e = __builtin_amdgcn_exp2f(x * q);
  return x * __builtin_amdgcn_rcpf(1.0f + e);
}

// (R x C) fp32 -> (C x R) fp16, one 32x32 tile per block, blockIdx.z = matrix idx
__global__ void transpose_cvt_kernel(const float* __restrict__ src,
                                     _Float16* __restrict__ dst, int R, int C) {
  __shared__ float tile[32][33];
  const float* s = src + (size_t)blockIdx.z * R * C;
  _Float16* d = dst + (size_t)blockIdx.z * R * C;
  int c0 = blockIdx.x * 32, r0 = blockIdx.y * 32;
  int tx = threadIdx.x, ty = threadIdx.y;
  for (int i = ty; i < 32; i += 8)
    tile[i][tx] = s[(size_t)(r0 + i) * C + (c0 + tx)];
  __syncthreads();
  for (int i = ty; i < 32; i += 8)
    d[(size_t)(c0 + i) * R + (r0 + tx)] = (_Float16)tile[tx][i];
}

// A-fragment addresses (16B runs, row-major weights)
#define A1ADDR(mi, ks) (W1s + (size_t)(chbase + w * 32 + (mi)*16 + lr) * MAXC + (ks)*32 + lg * 8)
#define A2ADDR(mi, ks) (W2t + (size_t)(w * 32 + (mi)*16 + lr) * HID + chbase + (ks)*32 + lg * 8)

// Prefetch first two ks of a phase into AF (issued BEFORE the barrier; the
// barrier asm's "memory" clobber pins the issue point).
#define PREFETCH(AADDR)                          \
  AF[0][0] = *(const f16x8*)AADDR(0, 0);         \
  AF[0][1] = *(const f16x8*)AADDR(1, 0);         \
  AF[1][0] = *(const f16x8*)AADDR(0, 1);         \
  AF[1][1] = *(const f16x8*)AADDR(1, 1);

// One GEMM phase: 8 ks steps, rolling depth-2 A-frag refill, B from LDS.
#define RUN_PHASE(AADDR, BS, ACC)                                              \
  _Pragma("unroll")                                                            \
  for (int ks = 0; ks < 8; ++ks) {                                             \
    f16x8 a0 = AF[ks & 1][0], a1 = AF[ks & 1][1];                              \
    if (ks < 6) {                                                              \
      AF[ks & 1][0] = *(const f16x8*)AADDR(0, ks + 2);                         \
      AF[ks & 1][1] = *(const f16x8*)AADDR(1, ks + 2);                         \
    }                                                                          \
    f16x8 bf[4];                                                               \
    _Pragma("unroll")                                                          \
    for (int ni = 0; ni < 4; ++ni) {                                           \
      int t = ni * 16 + lr;                                                    \
      bf[ni] = *(const f16x8*)(&BS[t * 256 + ((ks * 32 + lg * 8) ^ ((t & 7) << 3))]); \
    }                                                                          \
    __builtin_amdgcn_s_setprio(1);                                             \
    _Pragma("unroll")                                                          \
    for (int ni = 0; ni < 4; ++ni) {                                           \
      ACC[0][ni] = __builtin_amdgcn_mfma_f32_16x16x32_f16(a0, bf[ni], ACC[0][ni], 0, 0, 0); \
      ACC[1][ni] = __builtin_amdgcn_mfma_f32_16x16x32_f16(a1, bf[ni], ACC[1][ni], 0, 0, 0); \
    }                                                                          \
    __builtin_amdgcn_s_setprio(0);                                             \
  }

__global__ __launch_bounds__(512, 4)
void fused_sess_proj_kernel(const float* __restrict__ x,
                            const int* __restrict__ sess_ids,
                            const int* __restrict__ seq_lens,
                            const _Float16* __restrict__ W1t,   // [8][HID][MAXC]
                            const float* __restrict__ b_sess,   // [8][HID]
                            const _Float16* __restrict__ W2t,   // [NSRC][HID]
                            const float* __restrict__ b2,       // [NSRC]
                            float* __restrict__ out) {
  int wg = blockIdx.x;
  int b = wg >> 6;
  int t0 = (wg & 63) * TT;
  int seqlen = seq_lens[b];
  int tid = threadIdx.x;

  if (t0 >= seqlen) {  // fully masked tile: just write zeros (d_out is poisoned)
    int row = tid >> 1;
    int part = tid & 1;
    float* po = out + ((size_t)b * NSRC + row) * MAXT + t0 + part * 32;
    f32x4 z = {0.f, 0.f, 0.f, 0.f};
    #pragma unroll
    for (int i = 0; i < 8; ++i) *(f32x4*)(po + i * 4) = z;
    return;
  }

  // swizzled [t][col] layouts: f16 idx = t*256 + (col ^ ((t&7)<<3))
  __shared__ _Float16 Xs[TT * MAXC];  // 32 KB
  __shared__ _Float16 Hs[TT * 256];   // 32 KB (one 256-row h chunk at a time)

  int lane = tid & 63;
  int w = tid >> 6;    // wave 0..7
  int lg = lane >> 4;  // k-group / row-group
  int lr = lane & 15;  // m-row (A) / n-col (B,D)
  int sid = sess_ids[b];
  const _Float16* W1s = W1t + (size_t)sid * HID * MAXC;

  // ---- stage X^T tile: channel-PAIR per thread -> packed f16x2 dword writes ----
  // thread: c2=(tid&127)*2, th=tid>>7 owns t-local [th*16, th*16+16)
  {
    int c2 = (tid & 127) * 2;
    int th = tid >> 7;
    const float* xp = x + ((size_t)b * MAXC + c2) * MAXT + t0 + th * 16;
    f32x4 va[4], vb[4];
    #pragma unroll
    for (int i = 0; i < 4; ++i) va[i] = *(const f32x4*)(xp + i * 4);
    #pragma unroll
    for (int i = 0; i < 4; ++i) vb[i] = *(const f32x4*)(xp + MAXT + i * 4);
    #pragma unroll
    for (int k = 0; k < 16; ++k) {
      int t = th * 16 + k;
      fp16v2 p = __builtin_amdgcn_cvt_pkrtz(va[k >> 2][k & 3], vb[k >> 2][k & 3]);
      *(fp16v2*)(&Xs[t * 256 + (c2 ^ ((t & 7) << 3))]) = p;
    }
  }

  f16x8 AF[2][2];
  int chbase = 0;
  PREFETCH(A1ADDR);  // G1-c0 ks0/1, in flight across bar1

  // accumulators: acc2 persists across both chunks (bias-init)
  f32x4 acc2[2][4], acc1[2][4];
  #pragma unroll
  for (int mi = 0; mi < 2; ++mi) {
    f32x4 bv2 = *(const f32x4*)(b2 + w * 32 + mi * 16 + lg * 4);
    f32x4 bv1 = *(const f32x4*)(b_sess + sid * HID + w * 32 + mi * 16 + lg * 4);
    #pragma unroll
    for (int ni = 0; ni < 4; ++ni) { acc2[mi][ni] = bv2; acc1[mi][ni] = bv1; }
  }

  BAR();  // Xs visible

  // ================= GEMM1 ch0 =================
  RUN_PHASE(A1ADDR, Xs, acc1);

  // gelu(acc1) -> Hs; re-init acc1 with ch1 bias
  #pragma unroll
  for (int mi = 0; mi < 2; ++mi) {
    int hh = w * 32 + mi * 16 + lg * 4;
    #pragma unroll
    for (int ni = 0; ni < 4; ++ni) {
      int t = ni * 16 + lr;
      f16x4 g;
      #pragma unroll
      for (int r = 0; r < 4; ++r) g[r] = (_Float16)gelu_fast(acc1[mi][ni][r]);
      *(f16x4*)(&Hs[t * 256 + (hh ^ ((t & 7) << 3))]) = g;
    }
  }
  #pragma unroll
  for (int mi = 0; mi < 2; ++mi) {
    f32x4 bv1 = *(const f32x4*)(b_sess + sid * HID + 256 + w * 32 + mi * 16 + lg * 4);
    #pragma unroll
    for (int ni = 0; ni < 4; ++ni) acc1[mi][ni] = bv1;
  }

  PREFETCH(A2ADDR);  // G2-c0 ks0/1 (chbase still 0)
  BAR();  // Hs(ch0) visible

  // ================= GEMM2 ch0 =================
  RUN_PHASE(A2ADDR, Hs, acc2);

  chbase = 256;
  PREFETCH(A1ADDR);  // G1-c1 ks0/1
  BAR();  // all waves done reading Hs(ch0)

  // ================= GEMM1 ch1 =================
  RUN_PHASE(A1ADDR, Xs, acc1);

  // gelu(acc1) -> Hs (ch1)
  #pragma unroll
  for (int mi = 0; mi < 2; ++mi) {
    int hh = w * 32 + mi * 16 + lg * 4;
    #pragma unroll
    for (int ni = 0; ni < 4; ++ni) {
      int t = ni * 16 + lr;
      f16x4 g;
      #pragma unroll
      for (int r = 0; r < 4; ++r) g[r] = (_Float16)gelu_fast(acc1[mi][ni][r]);
      *(f16x4*)(&Hs[t * 256 + (hh ^ ((t & 7) << 3))]) = g;
    }
  }

  PREFETCH(A2ADDR);  // G2-c1 ks0/1 (chbase 256)
  BAR();  // Hs(ch1) visible

  // ================= GEMM2 ch1 =================
  RUN_PHASE(A2ADDR, Hs, acc2);

  // ---- epilogue: time mask + fp32 store ----
  #pragma unroll
  for (int mi = 0; mi < 2; ++mi) {
    int s0 = w * 32 + mi * 16 + lg * 4;
    #pragma unroll
    for (int ni = 0; ni < 4; ++ni) {
      int t = t0 + ni * 16 + lr;
      float m = (t < seqlen) ? 1.0f : 0.0f;
      #pragma unroll
      for (int r = 0; r < 4; ++r)
        out[((size_t)b * NSRC + s0 + r) * MAXT + t] = acc2[mi][ni][r] * m;
    }
  }
}

extern "C" void kernel_launch(void* const* d_in, const int* in_sizes, int n_in,
                              void* d_out, int out_size, void* d_ws, size_t ws_size,
                              hipStream_t stream) {
  const float* x      = (const float*)d_in[0];
  const int* sess     = (const int*)d_in[1];
  // d_in[2] = channel_counts: unused (x is already zero-padded past true channels)
  const int* seq      = (const int*)d_in[3];
  const float* W_sess = (const float*)d_in[4];
  const float* b_sess = (const float*)d_in[5];
  const float* W2     = (const float*)d_in[6];
  const float* b2     = (const float*)d_in[7];
  float* out = (float*)d_out;

  _Float16* W1t = (_Float16*)d_ws;                               // [8][512][256]
  _Float16* W2t = (_Float16*)((char*)d_ws + (size_t)8 * HID * MAXC * sizeof(_Float16));

  dim3 tb(32, 8);
  // W_sess: per session (256 x 512) -> (512 x 256) fp16
  transpose_cvt_kernel<<<dim3(HID / 32, MAXC / 32, 8), tb, 0, stream>>>(W_sess, W1t, MAXC, HID);
  // W2: (512 x 256) -> (256 x 512) fp16
  transpose_cvt_kernel<<<dim3(NSRC / 32, HID / 32, 1), tb, 0, stream>>>(W2, W2t, HID, NSRC);

  fused_sess_proj_kernel<<<dim3(NB * (MAXT / TT)), dim3(512), 0, stream>>>(
      x, sess, seq, W1t, b_sess, W2t, b2, out);
}